// Round 4
// baseline (181.084 us; speedup 1.0000x reference)
//
#include <hip/hip_runtime.h>

// Problem constants (from reference setup_inputs): B=16, C=4, H=W=1024.
#define B_  16
#define H_  1024
#define W_  1024
#define OW_ (2 * W_)       // 2048
#define OH_ (2 * H_)       // 2048

// Block layout: 34816 blocks total.
//   g <  32768 -> shuffle block: pixel-shuffle only (1:1 read:write, memcpy-like).
//   g >= 32768 -> cons block (2048 blocks): runs as a dispatch TAIL —
//                 reads batch-0 channels (12 MiB, L2/L3-hit) and does a
//                 nearly pure-write burst broadcasting the cons plane to
//                 all 16 batches. De-mixing the read and write streams
//                 phase-wise is the variable under test this round.

__global__ __launch_bounds__(256) void unsqueeze_cons_kernel(
    const float* __restrict__ in,
    float* __restrict__ out_x,
    float* __restrict__ out_cons)
{
    const int g = blockIdx.x;
    const long chanStride = (long)H_ * W_;           // 1,048,576

    if (g < 32768) {
        // ---------------- shuffle block ----------------
        const long idx = (long)g * 256 + threadIdx.x;
        const int c2 = (int)(idx & (W_ / 2 - 1));    // 0..511
        const int r  = (int)((idx >> 9) & (H_ - 1)); // 0..1023
        const int b  = (int)(idx >> 19);             // 0..15

        const long base = ((long)b * 4) * chanStride + (long)r * W_ + (long)c2 * 2;
        const float2 ch0 = *reinterpret_cast<const float2*>(in + base);
        const float2 ch1 = *reinterpret_cast<const float2*>(in + base + chanStride);
        const float2 ch2 = *reinterpret_cast<const float2*>(in + base + 2 * chanStride);
        const float2 ch3 = *reinterpret_cast<const float2*>(in + base + 3 * chanStride);

        // out_x[b, 2r+dr, 2c+dc] = in[b, dr+2*dc, r, c]
        const long orow0 = (long)b * OH_ * OW_ + (long)(2 * r) * OW_ + (long)c2 * 4;
        const long orow1 = orow0 + OW_;
        float4 x0 = {ch0.x, ch2.x, ch0.y, ch2.y};
        float4 x1 = {ch1.x, ch3.x, ch1.y, ch3.y};
        *reinterpret_cast<float4*>(out_x + orow0) = x0;
        *reinterpret_cast<float4*>(out_x + orow1) = x1;
    } else {
        // ---------------- cons block (tail) ----------------
        const long idx = (long)(g - 32768) * 256 + threadIdx.x;  // 0..524287
        const int c2 = (int)(idx & (W_ / 2 - 1));                // 0..511
        const int r  = (int)(idx >> 9);                          // 0..1023

        const long base0 = (long)r * W_ + (long)c2 * 2;
        const float2 a0 = *reinterpret_cast<const float2*>(in + base0);
        const float2 a1 = *reinterpret_cast<const float2*>(in + base0 + chanStride);
        const float2 a2 = *reinterpret_cast<const float2*>(in + base0 + 2 * chanStride);

        const float k3 = 1.0f / 3.0f;
        float2 s2, s1, s0;
        s2.x = (a0.x + 1.0f) * 0.5f;
        s2.y = (a0.y + 1.0f) * 0.5f;
        s1.x = (a0.x + a1.x + 1.0f) * k3;
        s1.y = (a0.y + a1.y + 1.0f) * k3;
        s0.x = (a0.x + a1.x + a2.x + 1.0f) * 0.25f;
        s0.y = (a0.y + a1.y + a2.y + 1.0f) * 0.25f;

        // cons row 2r   : (2c)->1.0, (2c+1)->s1
        // cons row 2r+1 : (2c)->s2,  (2c+1)->s0
        float4 c0 = {1.0f, s1.x, 1.0f, s1.y};
        float4 c1 = {s2.x, s0.x, s2.y, s0.y};

        const long prow0 = (long)(2 * r) * OW_ + (long)c2 * 4;
        const long prow1 = prow0 + OW_;
        #pragma unroll
        for (int b2 = 0; b2 < B_; ++b2) {
            const long boff = (long)b2 * OH_ * OW_;
            *reinterpret_cast<float4*>(out_cons + boff + prow0) = c0;
            *reinterpret_cast<float4*>(out_cons + boff + prow1) = c1;
        }
    }
}

extern "C" void kernel_launch(void* const* d_in, const int* in_sizes, int n_in,
                              void* d_out, int out_size, void* d_ws, size_t ws_size,
                              hipStream_t stream) {
    const float* in = (const float*)d_in[0];
    float* out_x    = (float*)d_out;                                   // (16,1,2048,2048)
    float* out_cons = (float*)d_out + (long)B_ * OH_ * OW_;            // (16,1,2048,2048)

    const int grid = 32768 + 2048;                                     // shuffle + cons tail
    unsqueeze_cons_kernel<<<grid, 256, 0, stream>>>(in, out_x, out_cons);
}

// Round 6
// 123.436 us; speedup vs baseline: 1.4670x; 1.4670x over previous
//
#include <hip/hip_runtime.h>

// Problem constants (from reference setup_inputs): B=16, C=4, H=W=1024.
#define B_  16
#define H_  1024
#define W_  1024
#define OW_ (2 * W_)       // 2048
#define OH_ (2 * H_)       // 2048
#define RB_ 16             // input rows per block (=> 256 KB contiguous output slab)

typedef float f32x4 __attribute__((ext_vector_type(4)));
typedef float f32x2 __attribute__((ext_vector_type(2)));

// 2048 blocks, all co-resident (8 blocks/CU x 256 CU, 32 waves/CU):
//   g <  1024 : shuffle block — owns (b, 16-row slab). Writes a 256 KB
//               CONTIGUOUS out_x slab row-by-row; reads 4 sequential
//               channel streams (64 KB each). Long same-direction bursts
//               per block = DRAM page locality (the variable under test).
//   g >= 1024 : cons block — owns (b, 16-row slab) of out_cons. Writes a
//               256 KB contiguous slab; reads batch-0 rows (16x reused
//               across b-blocks -> L2/L3-hit).
// All output stores are nontemporal (streaming, skip L2 allocation).

__global__ __launch_bounds__(256) void unsqueeze_cons_kernel(
    const float* __restrict__ in,
    float* __restrict__ out_x,
    float* __restrict__ out_cons)
{
    const int g = blockIdx.x;
    const int t = threadIdx.x;
    const long chanStride = (long)H_ * W_;           // 1,048,576

    if (g < 1024) {
        // ---------------- shuffle block ----------------
        const int b  = g >> 6;                       // 0..15
        const int r0 = (g & 63) * RB_;               // 0..1008
        const long inb  = ((long)b * 4) * chanStride;
        const long outb = (long)b * OH_ * OW_;

        for (int rr = 0; rr < RB_; ++rr) {
            const int r = r0 + rr;
            #pragma unroll
            for (int j = 0; j < 2; ++j) {
                const int c2 = t + 256 * j;          // 0..511
                const long base = inb + (long)r * W_ + (long)c2 * 2;
                const f32x2 ch0 = *reinterpret_cast<const f32x2*>(in + base);
                const f32x2 ch1 = *reinterpret_cast<const f32x2*>(in + base + chanStride);
                const f32x2 ch2 = *reinterpret_cast<const f32x2*>(in + base + 2 * chanStride);
                const f32x2 ch3 = *reinterpret_cast<const f32x2*>(in + base + 3 * chanStride);

                // out_x[b, 2r+dr, 2c+dc] = in[b, dr+2*dc, r, c]
                const long orow0 = outb + (long)(2 * r) * OW_ + (long)c2 * 4;
                f32x4 x0 = {ch0.x, ch2.x, ch0.y, ch2.y};
                f32x4 x1 = {ch1.x, ch3.x, ch1.y, ch3.y};
                __builtin_nontemporal_store(x0, reinterpret_cast<f32x4*>(out_x + orow0));
                __builtin_nontemporal_store(x1, reinterpret_cast<f32x4*>(out_x + orow0 + OW_));
            }
        }
    } else {
        // ---------------- cons block ----------------
        const int gg = g - 1024;
        const int b  = gg >> 6;                      // 0..15
        const int r0 = (gg & 63) * RB_;              // 0..1008
        const long outb = (long)b * OH_ * OW_;

        for (int rr = 0; rr < RB_; ++rr) {
            const int r = r0 + rr;
            #pragma unroll
            for (int j = 0; j < 2; ++j) {
                const int c2 = t + 256 * j;          // 0..511
                const long base0 = (long)r * W_ + (long)c2 * 2;
                const f32x2 a0 = *reinterpret_cast<const f32x2*>(in + base0);
                const f32x2 a1 = *reinterpret_cast<const f32x2*>(in + base0 + chanStride);
                const f32x2 a2 = *reinterpret_cast<const f32x2*>(in + base0 + 2 * chanStride);

                const float k3 = 1.0f / 3.0f;
                f32x2 s2, s1, s0;
                s2.x = (a0.x + 1.0f) * 0.5f;
                s2.y = (a0.y + 1.0f) * 0.5f;
                s1.x = (a0.x + a1.x + 1.0f) * k3;
                s1.y = (a0.y + a1.y + 1.0f) * k3;
                s0.x = (a0.x + a1.x + a2.x + 1.0f) * 0.25f;
                s0.y = (a0.y + a1.y + a2.y + 1.0f) * 0.25f;

                // cons row 2r: (2c)->1.0, (2c+1)->s1 ; row 2r+1: (2c)->s2, (2c+1)->s0
                f32x4 c0 = {1.0f, s1.x, 1.0f, s1.y};
                f32x4 c1 = {s2.x, s0.x, s2.y, s0.y};
                const long prow0 = outb + (long)(2 * r) * OW_ + (long)c2 * 4;
                __builtin_nontemporal_store(c0, reinterpret_cast<f32x4*>(out_cons + prow0));
                __builtin_nontemporal_store(c1, reinterpret_cast<f32x4*>(out_cons + prow0 + OW_));
            }
        }
    }
}

extern "C" void kernel_launch(void* const* d_in, const int* in_sizes, int n_in,
                              void* d_out, int out_size, void* d_ws, size_t ws_size,
                              hipStream_t stream) {
    const float* in = (const float*)d_in[0];
    float* out_x    = (float*)d_out;                                   // (16,1,2048,2048)
    float* out_cons = (float*)d_out + (long)B_ * OH_ * OW_;            // (16,1,2048,2048)

    const int grid = 2048;                                             // 1024 shuffle + 1024 cons
    unsqueeze_cons_kernel<<<grid, 256, 0, stream>>>(in, out_x, out_cons);
}